// Round 14
// baseline (181.071 us; speedup 1.0000x reference)
//
#include <hip/hip_runtime.h>
#include <hip/hip_bf16.h>
#include <cmath>

#define D_MODEL 1024
#define N_HEADS 16
#define HEAD_DIM 64
#define SEQ 2048
#define BATCH 2
#define MROWS (BATCH * SEQ)  // 4096

typedef __bf16 bf16;
typedef __bf16 bf16x8 __attribute__((ext_vector_type(8)));
typedef __bf16 bf16x4 __attribute__((ext_vector_type(4)));
typedef float f32x4 __attribute__((ext_vector_type(4)));

// async global->LDS, 16B per lane, linear dest (wave base + lane*16)
#define GLOAD16(g, l)                                                        \
    __builtin_amdgcn_global_load_lds(                                        \
        (const __attribute__((address_space(1))) void*)(g),                  \
        (__attribute__((address_space(3))) void*)(l), 16, 0, 0)

static __device__ __forceinline__ unsigned short bfbits(float f) {
    bf16 b = (bf16)f;
    return *(unsigned short*)&b;
}

// ---------------- fp32 -> bf16 convert (x) ----------------
__global__ __launch_bounds__(256) void cvt_x(const float* __restrict__ x,
                                             bf16* __restrict__ xb) {
    int i = blockIdx.x * 256 + threadIdx.x;
    float4 v = ((const float4*)x)[i];
    bf16x4 o = { (bf16)v.x, (bf16)v.y, (bf16)v.z, (bf16)v.w };
    ((bf16x4*)xb)[i] = o;
}

// ---------------- weight transpose + convert: wt[z][n][k] = W_z[k][n] ----------------
__global__ void cvt_wt(const float* __restrict__ Wq, const float* __restrict__ Wk,
                       const float* __restrict__ Wv, const float* __restrict__ Wo,
                       bf16* __restrict__ wt) {
    __shared__ float tile[32][33];
    int z = blockIdx.z;
    const float* W = (z == 0) ? Wq : (z == 1) ? Wk : (z == 2) ? Wv : Wo;
    int n0 = blockIdx.x * 32, k0 = blockIdx.y * 32;
    int tx = threadIdx.x, ty = threadIdx.y;
    tile[ty][tx] = W[(size_t)(k0 + ty) * D_MODEL + n0 + tx];
    __syncthreads();
    wt[(size_t)z * D_MODEL * D_MODEL + (size_t)(n0 + ty) * D_MODEL + k0 + tx] =
        (bf16)tile[tx][ty];
}

// ---------------- GEMM: Y[M,N] = A[M,K] @ Wt[N,K]^T + bias, BK=64 ----------------
// Staging via global_load_lds, 128B LDS rows, 8 slots/row. Write: linear dest,
// source col8 = slot ^ (row&7). Read: slot = (kc*4+h) ^ (r&7) -> k = kc*32+h*8.
// 16 K-iters (vs 32 at BK=32): half the barriers.
template <int MODE>
__global__ __launch_bounds__(256) void gemm_k(const bf16* __restrict__ A,
                                              const bf16* __restrict__ Bt,
                                              const float* __restrict__ b0,
                                              const float* __restrict__ b1,
                                              const float* __restrict__ b2,
                                              void* __restrict__ outp) {
    constexpr int BM = 128, BK = 64, KDIM = D_MODEL;
    __shared__ alignas(16) bf16 As[BM * BK];   // 16 KB
    __shared__ alignas(16) bf16 Bs[BM * BK];   // 16 KB
    char* Asb = (char*)As;
    char* Bsb = (char*)Bs;
    const int tid = threadIdx.x;
    const int wid = tid >> 6, lane = tid & 63;
    const int m0 = blockIdx.y * BM, n0 = blockIdx.x * BM;
    const int wr = (wid >> 1) * 64, wc = (wid & 1) * 64;
    const int hh = lane >> 4, ml = lane & 15;
    f32x4 acc[4][4] = {};

    for (int k0 = 0; k0 < KDIM; k0 += BK) {
        __syncthreads();
#pragma unroll
        for (int c = 0; c < 4; ++c) {
            const int q = c * 4 + wid;                // chunk 0..15 (wave-uniform)
            const int row = q * 8 + (lane >> 3);      // 0..127
            const int col8 = (lane & 7) ^ (row & 7);  // inverse swizzle
            GLOAD16(&A[(size_t)(m0 + row) * KDIM + k0 + col8 * 8], Asb + q * 1024);
            GLOAD16(&Bt[(size_t)(n0 + row) * KDIM + k0 + col8 * 8], Bsb + q * 1024);
        }
        __syncthreads();  // compiler drains vmcnt before barrier
#pragma unroll
        for (int kc = 0; kc < 2; ++kc) {
            bf16x8 a[4], b[4];
#pragma unroll
            for (int m = 0; m < 4; ++m) {
                int r = wr + m * 16 + ml;
                int slot = ((kc << 2) | hh) ^ (r & 7);
                a[m] = *(bf16x8*)(Asb + r * 128 + slot * 16);
            }
#pragma unroll
            for (int n = 0; n < 4; ++n) {
                int r = wc + n * 16 + ml;
                int slot = ((kc << 2) | hh) ^ (r & 7);
                b[n] = *(bf16x8*)(Bsb + r * 128 + slot * 16);
            }
#pragma unroll
            for (int m = 0; m < 4; ++m)
#pragma unroll
                for (int n = 0; n < 4; ++n)
                    acc[m][n] =
                        __builtin_amdgcn_mfma_f32_16x16x32_bf16(a[m], b[n], acc[m][n], 0, 0, 0);
        }
    }

    const int z = n0 >> 10;
    const float* bias = (MODE == 1) ? b0 : ((z == 0) ? b0 : (z == 1) ? b1 : b2);
#pragma unroll
    for (int m = 0; m < 4; ++m)
#pragma unroll
        for (int n = 0; n < 4; ++n)
#pragma unroll
            for (int r = 0; r < 4; ++r) {
                int grow = m0 + wr + m * 16 + hh * 4 + r;
                int gcol = n0 + wc + n * 16 + ml;
                if (MODE == 0) {
                    int colN = gcol & 1023;
                    float val = acc[m][n][r] + bias[colN];
                    int b_ = grow >> 11, s_ = grow & 2047;
                    int h = colN >> 6, hd = colN & 63;
                    if (z == 2) {
                        ((bf16*)outp)[(size_t)z * 4194304 +
                                      ((size_t)(b_ * N_HEADS + h) * HEAD_DIM + hd) * SEQ + s_] =
                            (bf16)val;
                    } else {
                        ((bf16*)outp)[(size_t)z * 4194304 +
                                      ((size_t)(b_ * N_HEADS + h) * SEQ + s_) * HEAD_DIM + hd] =
                            (bf16)val;
                    }
                } else {
                    float val = acc[m][n][r] + bias[gcol];
                    ((float*)outp)[(size_t)grow * D_MODEL + gcol] = val;
                }
            }
}

// ---------------- flash attention: balanced complement pairs ----------------
// grid 1024 x 256 threads (4 waves). Block (p, bh) handles q-blocks {p, 63-p}:
// block total = 33 tiles CONSTANT -> every CU carries equal work regardless of
// block->CU assignment (4 blocks/CU at 34KB LDS). Wave role rotation
// (wid + blockIdx>>8)&3 spreads roles across co-resident blocks per SIMD.
// Split-K halves per q-block merge via LDS + one barrier (as before).
__global__ __launch_bounds__(256) void attn_k(const bf16* __restrict__ Qg,
                                              const bf16* __restrict__ Kg,
                                              const bf16* __restrict__ VTg,
                                              bf16* __restrict__ AO) {
    __shared__ alignas(16) unsigned int Pk[4][2][16][32];  // 16 KB packed P
    __shared__ alignas(16) f32x4 Og[2][2][4][64];          // 16 KB merge
    __shared__ float Mg[2][2][64];                         // 1 KB
    __shared__ float Lg[2][2][64];                         // 1 KB
    const int tid = threadIdx.x, wid = tid >> 6, lane = tid & 63;
    const int m = lane & 15, h = lane >> 4;
    const int widr = (wid + (blockIdx.x >> 8)) & 3;  // rotate roles across residents
    const int pair = widr & 1, half = widr >> 1;
    const int p = blockIdx.x >> 5;      // 0..31
    const int bh = blockIdx.x & 31;
    const int j = pair ? (63 - p) : p;  // complement pair per block
    const int q0 = j * 32;
    const size_t base = (size_t)bh * SEQ * HEAD_DIM;
    const bf16* VT = VTg + (size_t)bh * HEAD_DIM * SEQ;
    const int swz = (m & 7) << 2;

    bf16x8 aq[2][2];
#pragma unroll
    for (int sub = 0; sub < 2; ++sub)
#pragma unroll
        for (int kc = 0; kc < 2; ++kc)
            aq[sub][kc] = *(const bf16x8*)
                &Qg[base + (size_t)(q0 + sub * 16 + m) * HEAD_DIM + kc * 32 + h * 8];

    f32x4 o[2][4] = {};
    float mrow[2] = {-__builtin_inff(), -__builtin_inff()};
    float lrow[2] = {0.f, 0.f};

    const int nt = (j >> 1) + 1;
    const int nh0 = (nt + 1) >> 1;
    const int itb = half ? nh0 : 0;
    const int ite = half ? nt : nh0;

    bf16x8 kf[4][2];
    if (itb < ite) {
        const int t0p = itb * 64;
#pragma unroll
        for (int tf = 0; tf < 4; ++tf)
#pragma unroll
            for (int kc = 0; kc < 2; ++kc)
                kf[tf][kc] = *(const bf16x8*)
                    &Kg[base + (size_t)(t0p + tf * 16 + m) * HEAD_DIM + kc * 32 + h * 8];
    }

    for (int it = itb; it < ite; ++it) {
        const int t0 = it * 64;

        // ---- QK^T SWAPPED: lane holds q=m, t=tf*16+h*4+r ----
        f32x4 s[2][4];
        __builtin_amdgcn_s_setprio(1);
#pragma unroll
        for (int sub = 0; sub < 2; ++sub)
#pragma unroll
            for (int tf = 0; tf < 4; ++tf) {
                f32x4 z = {};
                z = __builtin_amdgcn_mfma_f32_16x16x32_bf16(kf[tf][0], aq[sub][0], z, 0, 0, 0);
                z = __builtin_amdgcn_mfma_f32_16x16x32_bf16(kf[tf][1], aq[sub][1], z, 0, 0, 0);
                s[sub][tf] = z;
            }
        __builtin_amdgcn_s_setprio(0);

        // V^T fragments (consumed after softmax)
        bf16x8 vf[4][2];
#pragma unroll
        for (int nf = 0; nf < 4; ++nf)
#pragma unroll
            for (int kc = 0; kc < 2; ++kc)
                vf[nf][kc] = *(const bf16x8*)
                    &VT[(size_t)(nf * 16 + m) * SEQ + t0 + kc * 32 + h * 8];

        // prefetch NEXT tile's K into dead kf registers
        if (it + 1 < ite) {
            const int t0n = t0 + 64;
#pragma unroll
            for (int tf = 0; tf < 4; ++tf)
#pragma unroll
                for (int kc = 0; kc < 2; ++kc)
                    kf[tf][kc] = *(const bf16x8*)
                        &Kg[base + (size_t)(t0n + tf * 16 + m) * HEAD_DIM + kc * 32 + h * 8];
        }

#pragma unroll
        for (int sub = 0; sub < 2; ++sub)
#pragma unroll
            for (int tf = 0; tf < 4; ++tf)
#pragma unroll
                for (int r = 0; r < 4; ++r) s[sub][tf][r] *= 0.125f;
        if (it == nt - 1) {
#pragma unroll
            for (int sub = 0; sub < 2; ++sub)
#pragma unroll
                for (int tf = 0; tf < 4; ++tf)
#pragma unroll
                    for (int r = 0; r < 4; ++r) {
                        int gq = q0 + sub * 16 + m;
                        int gt = t0 + tf * 16 + h * 4 + r;
                        if (gt > gq) s[sub][tf][r] = -__builtin_inff();
                    }
        }

        // ---- online softmax, per-lane row stats ----
#pragma unroll
        for (int sub = 0; sub < 2; ++sub) {
            float mx = s[sub][0][0];
#pragma unroll
            for (int tf = 0; tf < 4; ++tf)
#pragma unroll
                for (int r = 0; r < 4; ++r) mx = fmaxf(mx, s[sub][tf][r]);
            mx = fmaxf(mx, __shfl_xor(mx, 16));
            mx = fmaxf(mx, __shfl_xor(mx, 32));
            if (!__all(mx <= mrow[sub] + 8.f)) {
                float mn = fmaxf(mrow[sub], mx);
                float sf = __expf(mrow[sub] - mn);
                mrow[sub] = mn;
                lrow[sub] *= sf;
                float sfr[4];
#pragma unroll
                for (int r = 0; r < 4; ++r) sfr[r] = __shfl(sf, 20 * h + r);
#pragma unroll
                for (int nf = 0; nf < 4; ++nf)
#pragma unroll
                    for (int r = 0; r < 4; ++r) o[sub][nf][r] *= sfr[r];
            }
            float rs = 0.f;
#pragma unroll
            for (int tf = 0; tf < 4; ++tf)
#pragma unroll
                for (int r = 0; r < 4; ++r) {
                    float pv = __expf(s[sub][tf][r] - mrow[sub]);
                    s[sub][tf][r] = pv;
                    rs += pv;
                }
            rs += __shfl_xor(rs, 16);
            rs += __shfl_xor(rs, 32);
            lrow[sub] += rs;

            // pack P -> LDS
#pragma unroll
            for (int tf = 0; tf < 4; ++tf)
#pragma unroll
                for (int rp = 0; rp < 2; ++rp) {
                    unsigned int w = ((unsigned int)bfbits(s[sub][tf][2 * rp + 1]) << 16) |
                                     bfbits(s[sub][tf][2 * rp]);
                    Pk[wid][sub][m][(8 * tf + 2 * h + rp) ^ swz] = w;
                }
        }

        // ---- PV ----
        __builtin_amdgcn_s_setprio(1);
#pragma unroll
        for (int sub = 0; sub < 2; ++sub) {
#pragma unroll
            for (int kc = 0; kc < 2; ++kc) {
                bf16x8 ap = *(bf16x8*)&Pk[wid][sub][m][(16 * kc + 4 * h) ^ swz];
#pragma unroll
                for (int nf = 0; nf < 4; ++nf)
                    o[sub][nf] = __builtin_amdgcn_mfma_f32_16x16x32_bf16(
                        ap, vf[nf][kc], o[sub][nf], 0, 0, 0);
            }
        }
        __builtin_amdgcn_s_setprio(0);
    }

    // ---- split-K merge ----
    if (half == 1) {
#pragma unroll
        for (int sub = 0; sub < 2; ++sub) {
            Mg[pair][sub][lane] = mrow[sub];
            Lg[pair][sub][lane] = lrow[sub];
#pragma unroll
            for (int nf = 0; nf < 4; ++nf) Og[pair][sub][nf][lane] = o[sub][nf];
        }
    }
    __syncthreads();
    if (half == 0) {
        const int b_ = bh >> 4, hh = bh & 15;
#pragma unroll
        for (int sub = 0; sub < 2; ++sub) {
            float m1 = Mg[pair][sub][lane];
            float ms = fmaxf(mrow[sub], m1);
            float a0 = __expf(mrow[sub] - ms);
            float a1 = __expf(m1 - ms);
            float lc = lrow[sub] * a0 + Lg[pair][sub][lane] * a1;
            float a0r[4], a1r[4], lcr[4];
#pragma unroll
            for (int r = 0; r < 4; ++r) {
                a0r[r] = __shfl(a0, 20 * h + r);
                a1r[r] = __shfl(a1, 20 * h + r);
                lcr[r] = __shfl(lc, 20 * h + r);
            }
#pragma unroll
            for (int nf = 0; nf < 4; ++nf) {
                f32x4 o1 = Og[pair][sub][nf][lane];
#pragma unroll
                for (int r = 0; r < 4; ++r) {
                    float val = (o[sub][nf][r] * a0r[r] + o1[r] * a1r[r]) / lcr[r];
                    int s_ = q0 + sub * 16 + h * 4 + r;
                    AO[((size_t)(b_ * SEQ + s_)) * D_MODEL + hh * HEAD_DIM + nf * 16 + m] =
                        (bf16)val;
                }
            }
        }
    }
}

extern "C" void kernel_launch(void* const* d_in, const int* in_sizes, int n_in,
                              void* d_out, int out_size, void* d_ws, size_t ws_size,
                              hipStream_t stream) {
    const float* x  = (const float*)d_in[0];
    const float* Wq = (const float*)d_in[1];
    const float* bq = (const float*)d_in[2];
    const float* Wk = (const float*)d_in[3];
    const float* bk = (const float*)d_in[4];
    const float* Wv = (const float*)d_in[5];
    const float* bv = (const float*)d_in[6];
    const float* Wo = (const float*)d_in[7];
    const float* bo = (const float*)d_in[8];

    char* ws = (char*)d_ws;
    const size_t MB = 1u << 20;
    bf16* wt = (bf16*)ws;                  // 4 x [1024][1024] bf16 (QKV contiguous)
    bf16* xb = (bf16*)(ws + 8 * MB);       // [4096][1024] bf16
    bf16* Qb = (bf16*)(ws + 16 * MB);      // Q [32][2048][64]; K; V^T [32][64][2048]
    bf16* AO = (bf16*)(ws + 40 * MB);      // [4096][1024] bf16

    const size_t WSTRIDE = (size_t)D_MODEL * D_MODEL;

    cvt_x<<<dim3(MROWS * D_MODEL / 4 / 256), dim3(256), 0, stream>>>(x, xb);
    cvt_wt<<<dim3(32, 32, 4), dim3(32, 32), 0, stream>>>(Wq, Wk, Wv, Wo, wt);

    gemm_k<0><<<dim3(24, 32), dim3(256), 0, stream>>>(xb, wt, bq, bk, bv, Qb);

    bf16* Kb = Qb + 4194304;
    bf16* VTb = Qb + 2 * 4194304;
    attn_k<<<dim3(1024), dim3(256), 0, stream>>>(Qb, Kb, VTb, AO);

    gemm_k<1><<<dim3(8, 32), dim3(256), 0, stream>>>(AO, wt + 3 * WSTRIDE, bo, bo, bo, d_out);
}

// Round 15
// 164.827 us; speedup vs baseline: 1.0985x; 1.0985x over previous
//
#include <hip/hip_runtime.h>
#include <hip/hip_bf16.h>
#include <cmath>

#define D_MODEL 1024
#define N_HEADS 16
#define HEAD_DIM 64
#define SEQ 2048
#define BATCH 2
#define MROWS (BATCH * SEQ)  // 4096

typedef __bf16 bf16;
typedef __bf16 bf16x8 __attribute__((ext_vector_type(8)));
typedef __bf16 bf16x4 __attribute__((ext_vector_type(4)));
typedef float f32x4 __attribute__((ext_vector_type(4)));

// GEMM LDS swizzle (64B rows): byte = row*64 + (cbyte ^ (((row>>1)&3)<<4))
#define SWZG(row, cbyte) ((row) * 64 + ((cbyte) ^ ((((row) >> 1) & 3) << 4)))

// async global->LDS, 16B per lane, linear dest (wave base + lane*16)
#define GLOAD16(g, l)                                                        \
    __builtin_amdgcn_global_load_lds(                                        \
        (const __attribute__((address_space(1))) void*)(g),                  \
        (__attribute__((address_space(3))) void*)(l), 16, 0, 0)

static __device__ __forceinline__ unsigned short bfbits(float f) {
    bf16 b = (bf16)f;
    return *(unsigned short*)&b;
}

// ---------------- fp32 -> bf16 convert (x) ----------------
__global__ __launch_bounds__(256) void cvt_x(const float* __restrict__ x,
                                             bf16* __restrict__ xb) {
    int i = blockIdx.x * 256 + threadIdx.x;
    float4 v = ((const float4*)x)[i];
    bf16x4 o = { (bf16)v.x, (bf16)v.y, (bf16)v.z, (bf16)v.w };
    ((bf16x4*)xb)[i] = o;
}

// ---------------- weight transpose + convert: wt[z][n][k] = W_z[k][n] ----------------
__global__ void cvt_wt(const float* __restrict__ Wq, const float* __restrict__ Wk,
                       const float* __restrict__ Wv, const float* __restrict__ Wo,
                       bf16* __restrict__ wt) {
    __shared__ float tile[32][33];
    int z = blockIdx.z;
    const float* W = (z == 0) ? Wq : (z == 1) ? Wk : (z == 2) ? Wv : Wo;
    int n0 = blockIdx.x * 32, k0 = blockIdx.y * 32;
    int tx = threadIdx.x, ty = threadIdx.y;
    tile[ty][tx] = W[(size_t)(k0 + ty) * D_MODEL + n0 + tx];
    __syncthreads();
    wt[(size_t)z * D_MODEL * D_MODEL + (size_t)(n0 + ty) * D_MODEL + k0 + tx] =
        (bf16)tile[tx][ty];
}

// ---------------- GEMM: Y[M,N] = A[M,K] @ Wt[N,K]^T + bias (BK=32, R12-proven) ----------------
// MODE 0: fused QKV, N=3072. z=0 -> Q*0.125 [bh][t][d] (attn scale pre-folded),
// z=1 -> K[bh][t][d], z=2 -> V^T[bh][d][t].  MODE 1: out proj, f32 [M,N].
template <int MODE>
__global__ __launch_bounds__(256) void gemm_k(const bf16* __restrict__ A,
                                              const bf16* __restrict__ Bt,
                                              const float* __restrict__ b0,
                                              const float* __restrict__ b1,
                                              const float* __restrict__ b2,
                                              void* __restrict__ outp) {
    constexpr int BM = 128, BK = 32, KDIM = D_MODEL;
    __shared__ alignas(16) bf16 As[BM * BK];
    __shared__ alignas(16) bf16 Bs[BM * BK];
    char* Asb = (char*)As;
    char* Bsb = (char*)Bs;
    const int tid = threadIdx.x;
    const int wid = tid >> 6, lane = tid & 63;
    const int m0 = blockIdx.y * BM, n0 = blockIdx.x * BM;
    const int wr = (wid >> 1) * 64, wc = (wid & 1) * 64;
    f32x4 acc[4][4] = {};

    for (int k0 = 0; k0 < KDIM; k0 += BK) {
        __syncthreads();
#pragma unroll
        for (int c = 0; c < 2; ++c) {
            const int q = c * 4 + wid;
            const int row = q * 16 + (lane >> 2);
            const int col = (lane & 3) ^ ((row >> 1) & 3);
            GLOAD16(&A[(size_t)(m0 + row) * KDIM + k0 + col * 8], Asb + q * 1024);
            GLOAD16(&Bt[(size_t)(n0 + row) * KDIM + k0 + col * 8], Bsb + q * 1024);
        }
        __syncthreads();
        const int cb = (lane >> 4) * 16;
        bf16x8 a[4], b[4];
#pragma unroll
        for (int m = 0; m < 4; ++m) {
            int r = wr + m * 16 + (lane & 15);
            a[m] = *(bf16x8*)(Asb + SWZG(r, cb));
        }
#pragma unroll
        for (int n = 0; n < 4; ++n) {
            int r = wc + n * 16 + (lane & 15);
            b[n] = *(bf16x8*)(Bsb + SWZG(r, cb));
        }
#pragma unroll
        for (int m = 0; m < 4; ++m)
#pragma unroll
            for (int n = 0; n < 4; ++n)
                acc[m][n] = __builtin_amdgcn_mfma_f32_16x16x32_bf16(a[m], b[n], acc[m][n], 0, 0, 0);
    }

    const int z = n0 >> 10;
    const float* bias = (MODE == 1) ? b0 : ((z == 0) ? b0 : (z == 1) ? b1 : b2);
#pragma unroll
    for (int m = 0; m < 4; ++m)
#pragma unroll
        for (int n = 0; n < 4; ++n)
#pragma unroll
            for (int r = 0; r < 4; ++r) {
                int grow = m0 + wr + m * 16 + (lane >> 4) * 4 + r;
                int gcol = n0 + wc + n * 16 + (lane & 15);
                if (MODE == 0) {
                    int colN = gcol & 1023;
                    float val = acc[m][n][r] + bias[colN];
                    if (z == 0) val *= 0.125f;  // fold attn scale into Q
                    int b_ = grow >> 11, s_ = grow & 2047;
                    int h = colN >> 6, hd = colN & 63;
                    if (z == 2) {
                        ((bf16*)outp)[(size_t)z * 4194304 +
                                      ((size_t)(b_ * N_HEADS + h) * HEAD_DIM + hd) * SEQ + s_] =
                            (bf16)val;
                    } else {
                        ((bf16*)outp)[(size_t)z * 4194304 +
                                      ((size_t)(b_ * N_HEADS + h) * SEQ + s_) * HEAD_DIM + hd] =
                            (bf16)val;
                    }
                } else {
                    float val = acc[m][n][r] + bias[gcol];
                    ((float*)outp)[(size_t)grow * D_MODEL + gcol] = val;
                }
            }
}

// ---------------- flash attention: split-K pairs + swapped QK^T (R13) ----------------
// grid 512 x 512 threads. Block p' remapped pp = p<8 ? p : 23-p so the two
// co-resident blocks per CU (g, g+256 -> pp=a, 15-a) have per-SIMD work sums
// CONSTANT (33-s tiles): removes the CU-level tail that capped occupancy at 20%.
__global__ __launch_bounds__(512) void attn_k(const bf16* __restrict__ Qg,
                                              const bf16* __restrict__ Kg,
                                              const bf16* __restrict__ VTg,
                                              bf16* __restrict__ AO) {
    __shared__ alignas(16) unsigned int Pk[8][2][16][32];  // 32 KB packed P
    __shared__ alignas(16) f32x4 Og[4][2][4][64];          // 32 KB merge
    __shared__ float Mg[4][2][64];                         // 2 KB
    __shared__ float Lg[4][2][64];                         // 2 KB
    const int tid = threadIdx.x, wid = tid >> 6, lane = tid & 63;
    const int m = lane & 15, h = lane >> 4;
    const int pair = wid & 3, half = wid >> 2;
    const int p = blockIdx.x >> 5;
    const int bh = blockIdx.x & 31;
    const int pp = (p < 8) ? p : 23 - p;   // complement pairing of co-resident blocks
    const int j = 63 - (pp * 4 + pair);    // 0..63
    const int q0 = j * 32;
    const size_t base = (size_t)bh * SEQ * HEAD_DIM;
    const bf16* VT = VTg + (size_t)bh * HEAD_DIM * SEQ;
    const int swz = (m & 7) << 2;

    bf16x8 aq[2][2];
#pragma unroll
    for (int sub = 0; sub < 2; ++sub)
#pragma unroll
        for (int kc = 0; kc < 2; ++kc)
            aq[sub][kc] = *(const bf16x8*)
                &Qg[base + (size_t)(q0 + sub * 16 + m) * HEAD_DIM + kc * 32 + h * 8];

    f32x4 o[2][4] = {};
    float mrow[2] = {-__builtin_inff(), -__builtin_inff()};
    float lrow[2] = {0.f, 0.f};

    const int nt = (j >> 1) + 1;
    const int nh0 = (nt + 1) >> 1;
    const int itb = half ? nh0 : 0;
    const int ite = half ? nt : nh0;

    bf16x8 kf[4][2];
    if (itb < ite) {
        const int t0p = itb * 64;
#pragma unroll
        for (int tf = 0; tf < 4; ++tf)
#pragma unroll
            for (int kc = 0; kc < 2; ++kc)
                kf[tf][kc] = *(const bf16x8*)
                    &Kg[base + (size_t)(t0p + tf * 16 + m) * HEAD_DIM + kc * 32 + h * 8];
    }

    for (int it = itb; it < ite; ++it) {
        const int t0 = it * 64;

        // ---- QK^T SWAPPED: lane holds q=m, t=tf*16+h*4+r ----
        f32x4 s[2][4];
        __builtin_amdgcn_s_setprio(1);
#pragma unroll
        for (int sub = 0; sub < 2; ++sub)
#pragma unroll
            for (int tf = 0; tf < 4; ++tf) {
                f32x4 z = {};
                z = __builtin_amdgcn_mfma_f32_16x16x32_bf16(kf[tf][0], aq[sub][0], z, 0, 0, 0);
                z = __builtin_amdgcn_mfma_f32_16x16x32_bf16(kf[tf][1], aq[sub][1], z, 0, 0, 0);
                s[sub][tf] = z;
            }
        __builtin_amdgcn_s_setprio(0);

        // V^T fragments (consumed after softmax)
        bf16x8 vf[4][2];
#pragma unroll
        for (int nf = 0; nf < 4; ++nf)
#pragma unroll
            for (int kc = 0; kc < 2; ++kc)
                vf[nf][kc] = *(const bf16x8*)
                    &VT[(size_t)(nf * 16 + m) * SEQ + t0 + kc * 32 + h * 8];

        // prefetch NEXT tile's K into dead kf registers
        if (it + 1 < ite) {
            const int t0n = t0 + 64;
#pragma unroll
            for (int tf = 0; tf < 4; ++tf)
#pragma unroll
                for (int kc = 0; kc < 2; ++kc)
                    kf[tf][kc] = *(const bf16x8*)
                        &Kg[base + (size_t)(t0n + tf * 16 + m) * HEAD_DIM + kc * 32 + h * 8];
        }

        if (it == nt - 1) {
#pragma unroll
            for (int sub = 0; sub < 2; ++sub)
#pragma unroll
                for (int tf = 0; tf < 4; ++tf)
#pragma unroll
                    for (int r = 0; r < 4; ++r) {
                        int gq = q0 + sub * 16 + m;
                        int gt = t0 + tf * 16 + h * 4 + r;
                        if (gt > gq) s[sub][tf][r] = -__builtin_inff();
                    }
        }

        // ---- online softmax, per-lane row stats ----
#pragma unroll
        for (int sub = 0; sub < 2; ++sub) {
            float mx = s[sub][0][0];
#pragma unroll
            for (int tf = 0; tf < 4; ++tf)
#pragma unroll
                for (int r = 0; r < 4; ++r) mx = fmaxf(mx, s[sub][tf][r]);
            mx = fmaxf(mx, __shfl_xor(mx, 16));
            mx = fmaxf(mx, __shfl_xor(mx, 32));
            if (!__all(mx <= mrow[sub] + 8.f)) {
                float mn = fmaxf(mrow[sub], mx);
                float sf = __expf(mrow[sub] - mn);
                mrow[sub] = mn;
                lrow[sub] *= sf;
                float sfr[4];
#pragma unroll
                for (int r = 0; r < 4; ++r) sfr[r] = __shfl(sf, 20 * h + r);
#pragma unroll
                for (int nf = 0; nf < 4; ++nf)
#pragma unroll
                    for (int r = 0; r < 4; ++r) o[sub][nf][r] *= sfr[r];
            }
            float rs = 0.f;
#pragma unroll
            for (int tf = 0; tf < 4; ++tf)
#pragma unroll
                for (int r = 0; r < 4; ++r) {
                    float pv = __expf(s[sub][tf][r] - mrow[sub]);
                    s[sub][tf][r] = pv;
                    rs += pv;
                }
            rs += __shfl_xor(rs, 16);
            rs += __shfl_xor(rs, 32);
            lrow[sub] += rs;

            // pack P -> LDS
#pragma unroll
            for (int tf = 0; tf < 4; ++tf)
#pragma unroll
                for (int rp = 0; rp < 2; ++rp) {
                    unsigned int w = ((unsigned int)bfbits(s[sub][tf][2 * rp + 1]) << 16) |
                                     bfbits(s[sub][tf][2 * rp]);
                    Pk[wid][sub][m][(8 * tf + 2 * h + rp) ^ swz] = w;
                }
        }

        // ---- PV ----
        __builtin_amdgcn_s_setprio(1);
#pragma unroll
        for (int sub = 0; sub < 2; ++sub) {
#pragma unroll
            for (int kc = 0; kc < 2; ++kc) {
                bf16x8 ap = *(bf16x8*)&Pk[wid][sub][m][(16 * kc + 4 * h) ^ swz];
#pragma unroll
                for (int nf = 0; nf < 4; ++nf)
                    o[sub][nf] = __builtin_amdgcn_mfma_f32_16x16x32_bf16(
                        ap, vf[nf][kc], o[sub][nf], 0, 0, 0);
            }
        }
        __builtin_amdgcn_s_setprio(0);
    }

    // ---- split-K merge ----
    if (half == 1) {
#pragma unroll
        for (int sub = 0; sub < 2; ++sub) {
            Mg[pair][sub][lane] = mrow[sub];
            Lg[pair][sub][lane] = lrow[sub];
#pragma unroll
            for (int nf = 0; nf < 4; ++nf) Og[pair][sub][nf][lane] = o[sub][nf];
        }
    }
    __syncthreads();
    if (half == 0) {
        const int b_ = bh >> 4, hh = bh & 15;
#pragma unroll
        for (int sub = 0; sub < 2; ++sub) {
            float m1 = Mg[pair][sub][lane];
            float ms = fmaxf(mrow[sub], m1);
            float a0 = __expf(mrow[sub] - ms);
            float a1 = __expf(m1 - ms);
            float lc = lrow[sub] * a0 + Lg[pair][sub][lane] * a1;
            float a0r[4], a1r[4], lcr[4];
#pragma unroll
            for (int r = 0; r < 4; ++r) {
                a0r[r] = __shfl(a0, 20 * h + r);
                a1r[r] = __shfl(a1, 20 * h + r);
                lcr[r] = __shfl(lc, 20 * h + r);
            }
#pragma unroll
            for (int nf = 0; nf < 4; ++nf) {
                f32x4 o1 = Og[pair][sub][nf][lane];
#pragma unroll
                for (int r = 0; r < 4; ++r) {
                    float val = (o[sub][nf][r] * a0r[r] + o1[r] * a1r[r]) / lcr[r];
                    int s_ = q0 + sub * 16 + h * 4 + r;
                    AO[((size_t)(b_ * SEQ + s_)) * D_MODEL + hh * HEAD_DIM + nf * 16 + m] =
                        (bf16)val;
                }
            }
        }
    }
}

extern "C" void kernel_launch(void* const* d_in, const int* in_sizes, int n_in,
                              void* d_out, int out_size, void* d_ws, size_t ws_size,
                              hipStream_t stream) {
    const float* x  = (const float*)d_in[0];
    const float* Wq = (const float*)d_in[1];
    const float* bq = (const float*)d_in[2];
    const float* Wk = (const float*)d_in[3];
    const float* bk = (const float*)d_in[4];
    const float* Wv = (const float*)d_in[5];
    const float* bv = (const float*)d_in[6];
    const float* Wo = (const float*)d_in[7];
    const float* bo = (const float*)d_in[8];

    char* ws = (char*)d_ws;
    const size_t MB = 1u << 20;
    bf16* wt = (bf16*)ws;                  // 4 x [1024][1024] bf16 (QKV contiguous)
    bf16* xb = (bf16*)(ws + 8 * MB);       // [4096][1024] bf16
    bf16* Qb = (bf16*)(ws + 16 * MB);      // Q*0.125 [32][2048][64]; K; V^T [32][64][2048]
    bf16* AO = (bf16*)(ws + 40 * MB);      // [4096][1024] bf16

    const size_t WSTRIDE = (size_t)D_MODEL * D_MODEL;

    cvt_x<<<dim3(MROWS * D_MODEL / 4 / 256), dim3(256), 0, stream>>>(x, xb);
    cvt_wt<<<dim3(32, 32, 4), dim3(32, 32), 0, stream>>>(Wq, Wk, Wv, Wo, wt);

    gemm_k<0><<<dim3(24, 32), dim3(256), 0, stream>>>(xb, wt, bq, bk, bv, Qb);

    bf16* Kb = Qb + 4194304;
    bf16* VTb = Qb + 2 * 4194304;
    attn_k<<<dim3(512), dim3(512), 0, stream>>>(Qb, Kb, VTb, AO);

    gemm_k<1><<<dim3(8, 32), dim3(256), 0, stream>>>(AO, wt + 3 * WSTRIDE, bo, bo, bo, d_out);
}

// Round 16
// 153.121 us; speedup vs baseline: 1.1825x; 1.0765x over previous
//
#include <hip/hip_runtime.h>
#include <hip/hip_bf16.h>
#include <cmath>

#define D_MODEL 1024
#define N_HEADS 16
#define HEAD_DIM 64
#define SEQ 2048
#define BATCH 2
#define MROWS (BATCH * SEQ)  // 4096

typedef __bf16 bf16;
typedef __bf16 bf16x8 __attribute__((ext_vector_type(8)));
typedef __bf16 bf16x4 __attribute__((ext_vector_type(4)));
typedef float f32x4 __attribute__((ext_vector_type(4)));

// GEMM LDS swizzle (64B rows): byte = row*64 + (cbyte ^ (((row>>1)&3)<<4))
#define SWZG(row, cbyte) ((row) * 64 + ((cbyte) ^ ((((row) >> 1) & 3) << 4)))

// async global->LDS, 16B per lane, linear dest (wave base + lane*16)
#define GLOAD16(g, l)                                                        \
    __builtin_amdgcn_global_load_lds(                                        \
        (const __attribute__((address_space(1))) void*)(g),                  \
        (__attribute__((address_space(3))) void*)(l), 16, 0, 0)

static __device__ __forceinline__ unsigned short bfbits(float f) {
    bf16 b = (bf16)f;
    return *(unsigned short*)&b;
}

// ---------------- fp32 -> bf16 convert (x) ----------------
__global__ __launch_bounds__(256) void cvt_x(const float* __restrict__ x,
                                             bf16* __restrict__ xb) {
    int i = blockIdx.x * 256 + threadIdx.x;
    float4 v = ((const float4*)x)[i];
    bf16x4 o = { (bf16)v.x, (bf16)v.y, (bf16)v.z, (bf16)v.w };
    ((bf16x4*)xb)[i] = o;
}

// ---------------- weight transpose + convert: wt[z][n][k] = W_z[k][n] ----------------
__global__ void cvt_wt(const float* __restrict__ Wq, const float* __restrict__ Wk,
                       const float* __restrict__ Wv, const float* __restrict__ Wo,
                       bf16* __restrict__ wt) {
    __shared__ float tile[32][33];
    int z = blockIdx.z;
    const float* W = (z == 0) ? Wq : (z == 1) ? Wk : (z == 2) ? Wv : Wo;
    int n0 = blockIdx.x * 32, k0 = blockIdx.y * 32;
    int tx = threadIdx.x, ty = threadIdx.y;
    tile[ty][tx] = W[(size_t)(k0 + ty) * D_MODEL + n0 + tx];
    __syncthreads();
    wt[(size_t)z * D_MODEL * D_MODEL + (size_t)(n0 + ty) * D_MODEL + k0 + tx] =
        (bf16)tile[tx][ty];
}

// ---------------- GEMM: Y[M,N] = A[M,K] @ Wt[N,K]^T + bias (BK=32, R12-proven) ----------------
// MODE 0: fused QKV, N=3072. z=0 -> Q*0.125 [bh][t][d] (attn scale pre-folded),
// z=1 -> K[bh][t][d], z=2 -> V^T[bh][d][t].  MODE 1: out proj, f32 [M,N].
template <int MODE>
__global__ __launch_bounds__(256) void gemm_k(const bf16* __restrict__ A,
                                              const bf16* __restrict__ Bt,
                                              const float* __restrict__ b0,
                                              const float* __restrict__ b1,
                                              const float* __restrict__ b2,
                                              void* __restrict__ outp) {
    constexpr int BM = 128, BK = 32, KDIM = D_MODEL;
    __shared__ alignas(16) bf16 As[BM * BK];
    __shared__ alignas(16) bf16 Bs[BM * BK];
    char* Asb = (char*)As;
    char* Bsb = (char*)Bs;
    const int tid = threadIdx.x;
    const int wid = tid >> 6, lane = tid & 63;
    const int m0 = blockIdx.y * BM, n0 = blockIdx.x * BM;
    const int wr = (wid >> 1) * 64, wc = (wid & 1) * 64;
    f32x4 acc[4][4] = {};

    for (int k0 = 0; k0 < KDIM; k0 += BK) {
        __syncthreads();
#pragma unroll
        for (int c = 0; c < 2; ++c) {
            const int q = c * 4 + wid;
            const int row = q * 16 + (lane >> 2);
            const int col = (lane & 3) ^ ((row >> 1) & 3);
            GLOAD16(&A[(size_t)(m0 + row) * KDIM + k0 + col * 8], Asb + q * 1024);
            GLOAD16(&Bt[(size_t)(n0 + row) * KDIM + k0 + col * 8], Bsb + q * 1024);
        }
        __syncthreads();
        const int cb = (lane >> 4) * 16;
        bf16x8 a[4], b[4];
#pragma unroll
        for (int m = 0; m < 4; ++m) {
            int r = wr + m * 16 + (lane & 15);
            a[m] = *(bf16x8*)(Asb + SWZG(r, cb));
        }
#pragma unroll
        for (int n = 0; n < 4; ++n) {
            int r = wc + n * 16 + (lane & 15);
            b[n] = *(bf16x8*)(Bsb + SWZG(r, cb));
        }
#pragma unroll
        for (int m = 0; m < 4; ++m)
#pragma unroll
            for (int n = 0; n < 4; ++n)
                acc[m][n] = __builtin_amdgcn_mfma_f32_16x16x32_bf16(a[m], b[n], acc[m][n], 0, 0, 0);
    }

    const int z = n0 >> 10;
    const float* bias = (MODE == 1) ? b0 : ((z == 0) ? b0 : (z == 1) ? b1 : b2);
#pragma unroll
    for (int m = 0; m < 4; ++m)
#pragma unroll
        for (int n = 0; n < 4; ++n)
#pragma unroll
            for (int r = 0; r < 4; ++r) {
                int grow = m0 + wr + m * 16 + (lane >> 4) * 4 + r;
                int gcol = n0 + wc + n * 16 + (lane & 15);
                if (MODE == 0) {
                    int colN = gcol & 1023;
                    float val = acc[m][n][r] + bias[colN];
                    if (z == 0) val *= 0.125f;  // fold attn scale into Q
                    int b_ = grow >> 11, s_ = grow & 2047;
                    int h = colN >> 6, hd = colN & 63;
                    if (z == 2) {
                        ((bf16*)outp)[(size_t)z * 4194304 +
                                      ((size_t)(b_ * N_HEADS + h) * HEAD_DIM + hd) * SEQ + s_] =
                            (bf16)val;
                    } else {
                        ((bf16*)outp)[(size_t)z * 4194304 +
                                      ((size_t)(b_ * N_HEADS + h) * SEQ + s_) * HEAD_DIM + hd] =
                            (bf16)val;
                    }
                } else {
                    float val = acc[m][n][r] + bias[gcol];
                    ((float*)outp)[(size_t)grow * D_MODEL + gcol] = val;
                }
            }
}

// ---------------- flash attention: split-K pairs + swapped QK^T ----------------
// grid 512 x 512 threads (8 waves = 4 split-K pairs). Block p's four pair-slots
// handle q-blocks {p, 31-p, 32+p, 63-p} (bijective over 0..63): per-BLOCK work
// = 66 tiles CONSTANT, so every CU gets equal work and equal finish time
// regardless of block->CU placement or dispatch order (no scheduler assumptions).
__global__ __launch_bounds__(512) void attn_k(const bf16* __restrict__ Qg,
                                              const bf16* __restrict__ Kg,
                                              const bf16* __restrict__ VTg,
                                              bf16* __restrict__ AO) {
    __shared__ alignas(16) unsigned int Pk[8][2][16][32];  // 32 KB packed P
    __shared__ alignas(16) f32x4 Og[4][2][4][64];          // 32 KB merge
    __shared__ float Mg[4][2][64];                         // 2 KB
    __shared__ float Lg[4][2][64];                         // 2 KB
    const int tid = threadIdx.x, wid = tid >> 6, lane = tid & 63;
    const int m = lane & 15, h = lane >> 4;
    const int pair = wid & 3, half = wid >> 2;
    const int p = blockIdx.x >> 5;      // 0..15
    const int bh = blockIdx.x & 31;
    // constant-work assignment: {p, 31-p, 32+p, 63-p}
    const int j = (pair & 2) ? ((pair & 1) ? (63 - p) : (32 + p))
                             : ((pair & 1) ? (31 - p) : p);
    const int q0 = j * 32;
    const size_t base = (size_t)bh * SEQ * HEAD_DIM;
    const bf16* VT = VTg + (size_t)bh * HEAD_DIM * SEQ;
    const int swz = (m & 7) << 2;

    bf16x8 aq[2][2];
#pragma unroll
    for (int sub = 0; sub < 2; ++sub)
#pragma unroll
        for (int kc = 0; kc < 2; ++kc)
            aq[sub][kc] = *(const bf16x8*)
                &Qg[base + (size_t)(q0 + sub * 16 + m) * HEAD_DIM + kc * 32 + h * 8];

    f32x4 o[2][4] = {};
    float mrow[2] = {-__builtin_inff(), -__builtin_inff()};
    float lrow[2] = {0.f, 0.f};

    const int nt = (j >> 1) + 1;
    const int nh0 = (nt + 1) >> 1;
    const int itb = half ? nh0 : 0;
    const int ite = half ? nt : nh0;

    bf16x8 kf[4][2];
    if (itb < ite) {
        const int t0p = itb * 64;
#pragma unroll
        for (int tf = 0; tf < 4; ++tf)
#pragma unroll
            for (int kc = 0; kc < 2; ++kc)
                kf[tf][kc] = *(const bf16x8*)
                    &Kg[base + (size_t)(t0p + tf * 16 + m) * HEAD_DIM + kc * 32 + h * 8];
    }

    for (int it = itb; it < ite; ++it) {
        const int t0 = it * 64;

        // ---- QK^T SWAPPED: lane holds q=m, t=tf*16+h*4+r ----
        f32x4 s[2][4];
        __builtin_amdgcn_s_setprio(1);
#pragma unroll
        for (int sub = 0; sub < 2; ++sub)
#pragma unroll
            for (int tf = 0; tf < 4; ++tf) {
                f32x4 z = {};
                z = __builtin_amdgcn_mfma_f32_16x16x32_bf16(kf[tf][0], aq[sub][0], z, 0, 0, 0);
                z = __builtin_amdgcn_mfma_f32_16x16x32_bf16(kf[tf][1], aq[sub][1], z, 0, 0, 0);
                s[sub][tf] = z;
            }
        __builtin_amdgcn_s_setprio(0);

        // V^T fragments (consumed after softmax)
        bf16x8 vf[4][2];
#pragma unroll
        for (int nf = 0; nf < 4; ++nf)
#pragma unroll
            for (int kc = 0; kc < 2; ++kc)
                vf[nf][kc] = *(const bf16x8*)
                    &VT[(size_t)(nf * 16 + m) * SEQ + t0 + kc * 32 + h * 8];

        // prefetch NEXT tile's K into dead kf registers
        if (it + 1 < ite) {
            const int t0n = t0 + 64;
#pragma unroll
            for (int tf = 0; tf < 4; ++tf)
#pragma unroll
                for (int kc = 0; kc < 2; ++kc)
                    kf[tf][kc] = *(const bf16x8*)
                        &Kg[base + (size_t)(t0n + tf * 16 + m) * HEAD_DIM + kc * 32 + h * 8];
        }

        if (it == nt - 1) {
#pragma unroll
            for (int sub = 0; sub < 2; ++sub)
#pragma unroll
                for (int tf = 0; tf < 4; ++tf)
#pragma unroll
                    for (int r = 0; r < 4; ++r) {
                        int gq = q0 + sub * 16 + m;
                        int gt = t0 + tf * 16 + h * 4 + r;
                        if (gt > gq) s[sub][tf][r] = -__builtin_inff();
                    }
        }

        // ---- online softmax, per-lane row stats ----
#pragma unroll
        for (int sub = 0; sub < 2; ++sub) {
            float mx = s[sub][0][0];
#pragma unroll
            for (int tf = 0; tf < 4; ++tf)
#pragma unroll
                for (int r = 0; r < 4; ++r) mx = fmaxf(mx, s[sub][tf][r]);
            mx = fmaxf(mx, __shfl_xor(mx, 16));
            mx = fmaxf(mx, __shfl_xor(mx, 32));
            if (!__all(mx <= mrow[sub] + 8.f)) {
                float mn = fmaxf(mrow[sub], mx);
                float sf = __expf(mrow[sub] - mn);
                mrow[sub] = mn;
                lrow[sub] *= sf;
                float sfr[4];
#pragma unroll
                for (int r = 0; r < 4; ++r) sfr[r] = __shfl(sf, 20 * h + r);
#pragma unroll
                for (int nf = 0; nf < 4; ++nf)
#pragma unroll
                    for (int r = 0; r < 4; ++r) o[sub][nf][r] *= sfr[r];
            }
            float rs = 0.f;
#pragma unroll
            for (int tf = 0; tf < 4; ++tf)
#pragma unroll
                for (int r = 0; r < 4; ++r) {
                    float pv = __expf(s[sub][tf][r] - mrow[sub]);
                    s[sub][tf][r] = pv;
                    rs += pv;
                }
            rs += __shfl_xor(rs, 16);
            rs += __shfl_xor(rs, 32);
            lrow[sub] += rs;

            // pack P -> LDS
#pragma unroll
            for (int tf = 0; tf < 4; ++tf)
#pragma unroll
                for (int rp = 0; rp < 2; ++rp) {
                    unsigned int w = ((unsigned int)bfbits(s[sub][tf][2 * rp + 1]) << 16) |
                                     bfbits(s[sub][tf][2 * rp]);
                    Pk[wid][sub][m][(8 * tf + 2 * h + rp) ^ swz] = w;
                }
        }

        // ---- PV ----
        __builtin_amdgcn_s_setprio(1);
#pragma unroll
        for (int sub = 0; sub < 2; ++sub) {
#pragma unroll
            for (int kc = 0; kc < 2; ++kc) {
                bf16x8 ap = *(bf16x8*)&Pk[wid][sub][m][(16 * kc + 4 * h) ^ swz];
#pragma unroll
                for (int nf = 0; nf < 4; ++nf)
                    o[sub][nf] = __builtin_amdgcn_mfma_f32_16x16x32_bf16(
                        ap, vf[nf][kc], o[sub][nf], 0, 0, 0);
            }
        }
        __builtin_amdgcn_s_setprio(0);
    }

    // ---- split-K merge ----
    if (half == 1) {
#pragma unroll
        for (int sub = 0; sub < 2; ++sub) {
            Mg[pair][sub][lane] = mrow[sub];
            Lg[pair][sub][lane] = lrow[sub];
#pragma unroll
            for (int nf = 0; nf < 4; ++nf) Og[pair][sub][nf][lane] = o[sub][nf];
        }
    }
    __syncthreads();
    if (half == 0) {
        const int b_ = bh >> 4, hh = bh & 15;
#pragma unroll
        for (int sub = 0; sub < 2; ++sub) {
            float m1 = Mg[pair][sub][lane];
            float ms = fmaxf(mrow[sub], m1);
            float a0 = __expf(mrow[sub] - ms);
            float a1 = __expf(m1 - ms);
            float lc = lrow[sub] * a0 + Lg[pair][sub][lane] * a1;
            float a0r[4], a1r[4], lcr[4];
#pragma unroll
            for (int r = 0; r < 4; ++r) {
                a0r[r] = __shfl(a0, 20 * h + r);
                a1r[r] = __shfl(a1, 20 * h + r);
                lcr[r] = __shfl(lc, 20 * h + r);
            }
#pragma unroll
            for (int nf = 0; nf < 4; ++nf) {
                f32x4 o1 = Og[pair][sub][nf][lane];
#pragma unroll
                for (int r = 0; r < 4; ++r) {
                    float val = (o[sub][nf][r] * a0r[r] + o1[r] * a1r[r]) / lcr[r];
                    int s_ = q0 + sub * 16 + h * 4 + r;
                    AO[((size_t)(b_ * SEQ + s_)) * D_MODEL + hh * HEAD_DIM + nf * 16 + m] =
                        (bf16)val;
                }
            }
        }
    }
}

extern "C" void kernel_launch(void* const* d_in, const int* in_sizes, int n_in,
                              void* d_out, int out_size, void* d_ws, size_t ws_size,
                              hipStream_t stream) {
    const float* x  = (const float*)d_in[0];
    const float* Wq = (const float*)d_in[1];
    const float* bq = (const float*)d_in[2];
    const float* Wk = (const float*)d_in[3];
    const float* bk = (const float*)d_in[4];
    const float* Wv = (const float*)d_in[5];
    const float* bv = (const float*)d_in[6];
    const float* Wo = (const float*)d_in[7];
    const float* bo = (const float*)d_in[8];

    char* ws = (char*)d_ws;
    const size_t MB = 1u << 20;
    bf16* wt = (bf16*)ws;                  // 4 x [1024][1024] bf16 (QKV contiguous)
    bf16* xb = (bf16*)(ws + 8 * MB);       // [4096][1024] bf16
    bf16* Qb = (bf16*)(ws + 16 * MB);      // Q*0.125 [32][2048][64]; K; V^T [32][64][2048]
    bf16* AO = (bf16*)(ws + 40 * MB);      // [4096][1024] bf16

    const size_t WSTRIDE = (size_t)D_MODEL * D_MODEL;

    cvt_x<<<dim3(MROWS * D_MODEL / 4 / 256), dim3(256), 0, stream>>>(x, xb);
    cvt_wt<<<dim3(32, 32, 4), dim3(32, 32), 0, stream>>>(Wq, Wk, Wv, Wo, wt);

    gemm_k<0><<<dim3(24, 32), dim3(256), 0, stream>>>(xb, wt, bq, bk, bv, Qb);

    bf16* Kb = Qb + 4194304;
    bf16* VTb = Qb + 2 * 4194304;
    attn_k<<<dim3(512), dim3(512), 0, stream>>>(Qb, Kb, VTb, AO);

    gemm_k<1><<<dim3(8, 32), dim3(256), 0, stream>>>(AO, wt + 3 * WSTRIDE, bo, bo, bo, d_out);
}

// Round 17
// 142.557 us; speedup vs baseline: 1.2702x; 1.0741x over previous
//
#include <hip/hip_runtime.h>
#include <hip/hip_bf16.h>
#include <cmath>

#define D_MODEL 1024
#define N_HEADS 16
#define HEAD_DIM 64
#define SEQ 2048
#define BATCH 2
#define MROWS (BATCH * SEQ)  // 4096

typedef __bf16 bf16;
typedef __bf16 bf16x8 __attribute__((ext_vector_type(8)));
typedef __bf16 bf16x4 __attribute__((ext_vector_type(4)));
typedef float f32x4 __attribute__((ext_vector_type(4)));

// GEMM LDS swizzle (64B rows): byte = row*64 + (cbyte ^ (((row>>1)&3)<<4))
#define SWZG(row, cbyte) ((row) * 64 + ((cbyte) ^ ((((row) >> 1) & 3) << 4)))

// async global->LDS, 16B per lane, linear dest (wave base + lane*16)
#define GLOAD16(g, l)                                                        \
    __builtin_amdgcn_global_load_lds(                                        \
        (const __attribute__((address_space(1))) void*)(g),                  \
        (__attribute__((address_space(3))) void*)(l), 16, 0, 0)

static __device__ __forceinline__ unsigned short bfbits(float f) {
    bf16 b = (bf16)f;
    return *(unsigned short*)&b;
}

// ---------------- fp32 -> bf16 convert (x) ----------------
__global__ __launch_bounds__(256) void cvt_x(const float* __restrict__ x,
                                             bf16* __restrict__ xb) {
    int i = blockIdx.x * 256 + threadIdx.x;
    float4 v = ((const float4*)x)[i];
    bf16x4 o = { (bf16)v.x, (bf16)v.y, (bf16)v.z, (bf16)v.w };
    ((bf16x4*)xb)[i] = o;
}

// ---------------- weight transpose + convert: wt[z][n][k] = W_z[k][n] ----------------
__global__ void cvt_wt(const float* __restrict__ Wq, const float* __restrict__ Wk,
                       const float* __restrict__ Wv, const float* __restrict__ Wo,
                       bf16* __restrict__ wt) {
    __shared__ float tile[32][33];
    int z = blockIdx.z;
    const float* W = (z == 0) ? Wq : (z == 1) ? Wk : (z == 2) ? Wv : Wo;
    int n0 = blockIdx.x * 32, k0 = blockIdx.y * 32;
    int tx = threadIdx.x, ty = threadIdx.y;
    tile[ty][tx] = W[(size_t)(k0 + ty) * D_MODEL + n0 + tx];
    __syncthreads();
    wt[(size_t)z * D_MODEL * D_MODEL + (size_t)(n0 + ty) * D_MODEL + k0 + tx] =
        (bf16)tile[tx][ty];
}

// ---------------- GEMM: Y[M,N] = A[M,K] @ Wt[N,K]^T + bias (BK=32, proven) ----------------
template <int MODE>
__global__ __launch_bounds__(256) void gemm_k(const bf16* __restrict__ A,
                                              const bf16* __restrict__ Bt,
                                              const float* __restrict__ b0,
                                              const float* __restrict__ b1,
                                              const float* __restrict__ b2,
                                              void* __restrict__ outp) {
    constexpr int BM = 128, BK = 32, KDIM = D_MODEL;
    __shared__ alignas(16) bf16 As[BM * BK];
    __shared__ alignas(16) bf16 Bs[BM * BK];
    char* Asb = (char*)As;
    char* Bsb = (char*)Bs;
    const int tid = threadIdx.x;
    const int wid = tid >> 6, lane = tid & 63;
    const int m0 = blockIdx.y * BM, n0 = blockIdx.x * BM;
    const int wr = (wid >> 1) * 64, wc = (wid & 1) * 64;
    f32x4 acc[4][4] = {};

    for (int k0 = 0; k0 < KDIM; k0 += BK) {
        __syncthreads();
#pragma unroll
        for (int c = 0; c < 2; ++c) {
            const int q = c * 4 + wid;
            const int row = q * 16 + (lane >> 2);
            const int col = (lane & 3) ^ ((row >> 1) & 3);
            GLOAD16(&A[(size_t)(m0 + row) * KDIM + k0 + col * 8], Asb + q * 1024);
            GLOAD16(&Bt[(size_t)(n0 + row) * KDIM + k0 + col * 8], Bsb + q * 1024);
        }
        __syncthreads();
        const int cb = (lane >> 4) * 16;
        bf16x8 a[4], b[4];
#pragma unroll
        for (int m = 0; m < 4; ++m) {
            int r = wr + m * 16 + (lane & 15);
            a[m] = *(bf16x8*)(Asb + SWZG(r, cb));
        }
#pragma unroll
        for (int n = 0; n < 4; ++n) {
            int r = wc + n * 16 + (lane & 15);
            b[n] = *(bf16x8*)(Bsb + SWZG(r, cb));
        }
#pragma unroll
        for (int m = 0; m < 4; ++m)
#pragma unroll
            for (int n = 0; n < 4; ++n)
                acc[m][n] = __builtin_amdgcn_mfma_f32_16x16x32_bf16(a[m], b[n], acc[m][n], 0, 0, 0);
    }

    const int z = n0 >> 10;
    const float* bias = (MODE == 1) ? b0 : ((z == 0) ? b0 : (z == 1) ? b1 : b2);
#pragma unroll
    for (int m = 0; m < 4; ++m)
#pragma unroll
        for (int n = 0; n < 4; ++n)
#pragma unroll
            for (int r = 0; r < 4; ++r) {
                int grow = m0 + wr + m * 16 + (lane >> 4) * 4 + r;
                int gcol = n0 + wc + n * 16 + (lane & 15);
                if (MODE == 0) {
                    int colN = gcol & 1023;
                    float val = acc[m][n][r] + bias[colN];
                    if (z == 0) val *= 0.125f;  // fold attn scale into Q
                    int b_ = grow >> 11, s_ = grow & 2047;
                    int h = colN >> 6, hd = colN & 63;
                    if (z == 2) {
                        ((bf16*)outp)[(size_t)z * 4194304 +
                                      ((size_t)(b_ * N_HEADS + h) * HEAD_DIM + hd) * SEQ + s_] =
                            (bf16)val;
                    } else {
                        ((bf16*)outp)[(size_t)z * 4194304 +
                                      ((size_t)(b_ * N_HEADS + h) * SEQ + s_) * HEAD_DIM + hd] =
                            (bf16)val;
                    }
                } else {
                    float val = acc[m][n][r] + bias[gcol];
                    ((float*)outp)[(size_t)grow * D_MODEL + gcol] = val;
                }
            }
}

// ---------------- flash attention: block-shared LDS K/V, counted-vmcnt pipeline ----------------
// grid 512 x 256 threads (4 waves x 32 q-rows = 128-row band). Heavy bands first.
// K and V^T tiles staged ONCE per block via global_load_lds into double-buffered
// XOR-swizzled LDS (4 loads/thread/tile), shared by all 4 waves: per-wave global
// traffic drops 16 loads/iter -> 0. Sync: counted vmcnt(4) + raw s_barrier x2
// per tile (next tile's loads stay in flight across barriers; no vmcnt(0) drain).
// Swapped QK^T + per-lane softmax + packed-P (per-sub LDS reuse) as R16.
__global__ __launch_bounds__(256) void attn_k(const bf16* __restrict__ Qg,
                                              const bf16* __restrict__ Kg,
                                              const bf16* __restrict__ VTg,
                                              bf16* __restrict__ AO) {
    __shared__ alignas(16) bf16 Ks[2][64 * 64];       // 16 KB
    __shared__ alignas(16) bf16 Vs[2][64 * 64];       // 16 KB
    __shared__ alignas(16) unsigned int Pk[4][16][32];  // 8 KB (per-sub reuse)
    const int tid = threadIdx.x, wid = tid >> 6, lane = tid & 63;
    const int m = lane & 15, h = lane >> 4;
    const int band = 15 - (int)(blockIdx.x >> 5);  // heavy first
    const int bh = blockIdx.x & 31;                // bh%8 fixes XCD -> KV L2 locality
    const int q0 = band * 128 + wid * 32;
    const size_t base = (size_t)bh * SEQ * HEAD_DIM;
    const bf16* VT = VTg + (size_t)bh * HEAD_DIM * SEQ;
    const int swz = (m & 7) << 2;
    const int nt_w = (q0 >> 6) + 1;        // this wave's tiles
    const int nt_blk = band * 2 + 2;       // block's staged tiles (max over waves)

    bf16x8 aq[2][2];
#pragma unroll
    for (int sub = 0; sub < 2; ++sub)
#pragma unroll
        for (int kc = 0; kc < 2; ++kc)
            aq[sub][kc] = *(const bf16x8*)
                &Qg[base + (size_t)(q0 + sub * 16 + m) * HEAD_DIM + kc * 32 + h * 8];

    f32x4 o[2][4] = {};
    float mrow[2] = {-__builtin_inff(), -__builtin_inff()};
    float lrow[2] = {0.f, 0.f};

    // stage tile T0 into buffer BUF: 4 GLOAD16/thread (2 K + 2 V).
    // LDS slot s of row holds global col 8*(s^(row&7)) (inverse swizzle at source).
#define STAGE(T0, BUF)                                                            \
    {                                                                             \
        _Pragma("unroll") for (int c = 0; c < 2; ++c) {                           \
            int lin = c * 256 + tid;                                              \
            int row = lin >> 3, sl = lin & 7;                                     \
            GLOAD16(&Kg[base + (size_t)((T0) + row) * HEAD_DIM +                  \
                        8 * (sl ^ (row & 7))],                                    \
                    (char*)&Ks[BUF][0] + lin * 16);                               \
            GLOAD16(&VT[(size_t)row * SEQ + (T0) + 8 * (sl ^ (row & 7))],         \
                    (char*)&Vs[BUF][0] + lin * 16);                               \
        }                                                                         \
    }

    STAGE(0, 0);
    int cur = 0;
    for (int it = 0; it < nt_blk; ++it) {
        if (it + 1 < nt_blk) {
            STAGE((it + 1) * 64, cur ^ 1);
            asm volatile("s_waitcnt vmcnt(4)" ::: "memory");  // current tile landed
        } else {
            asm volatile("s_waitcnt vmcnt(0)" ::: "memory");
        }
        __builtin_amdgcn_s_barrier();  // all waves' stage of tile it complete

        if (it < nt_w) {
            const int t0 = it * 64;
            char* Kb = (char*)&Ks[cur][0];
            char* Vb = (char*)&Vs[cur][0];
            bf16x8 kf[4][2], vf[4][2];
#pragma unroll
            for (int tf = 0; tf < 4; ++tf)
#pragma unroll
                for (int kc = 0; kc < 2; ++kc)
                    kf[tf][kc] = *(bf16x8*)(Kb + (16 * tf + m) * 128 +
                                            (((4 * kc + h) ^ (m & 7)) << 4));
#pragma unroll
            for (int nf = 0; nf < 4; ++nf)
#pragma unroll
                for (int kc = 0; kc < 2; ++kc)
                    vf[nf][kc] = *(bf16x8*)(Vb + (16 * nf + m) * 128 +
                                            (((4 * kc + h) ^ (m & 7)) << 4));

#pragma unroll
            for (int sub = 0; sub < 2; ++sub) {
                // ---- QK^T swapped: lane holds q=m, t=16tf+4h+r ----
                f32x4 s[4];
                __builtin_amdgcn_s_setprio(1);
#pragma unroll
                for (int tf = 0; tf < 4; ++tf) {
                    f32x4 z = {};
                    z = __builtin_amdgcn_mfma_f32_16x16x32_bf16(kf[tf][0], aq[sub][0], z, 0, 0, 0);
                    z = __builtin_amdgcn_mfma_f32_16x16x32_bf16(kf[tf][1], aq[sub][1], z, 0, 0, 0);
                    s[tf] = z;
                }
                __builtin_amdgcn_s_setprio(0);

                if (it == nt_w - 1) {
#pragma unroll
                    for (int tf = 0; tf < 4; ++tf)
#pragma unroll
                        for (int r = 0; r < 4; ++r) {
                            int gq = q0 + sub * 16 + m;
                            int gt = t0 + tf * 16 + h * 4 + r;
                            if (gt > gq) s[tf][r] = -__builtin_inff();
                        }
                }

                // ---- online softmax (per-lane stats, defer-max) ----
                float mx = s[0][0];
#pragma unroll
                for (int tf = 0; tf < 4; ++tf)
#pragma unroll
                    for (int r = 0; r < 4; ++r) mx = fmaxf(mx, s[tf][r]);
                mx = fmaxf(mx, __shfl_xor(mx, 16));
                mx = fmaxf(mx, __shfl_xor(mx, 32));
                if (!__all(mx <= mrow[sub] + 8.f)) {
                    float mn = fmaxf(mrow[sub], mx);
                    float sf = __expf(mrow[sub] - mn);
                    mrow[sub] = mn;
                    lrow[sub] *= sf;
                    float sfr[4];
#pragma unroll
                    for (int r = 0; r < 4; ++r) sfr[r] = __shfl(sf, 20 * h + r);
#pragma unroll
                    for (int nf = 0; nf < 4; ++nf)
#pragma unroll
                        for (int r = 0; r < 4; ++r) o[sub][nf][r] *= sfr[r];
                }
                float rs = 0.f;
#pragma unroll
                for (int tf = 0; tf < 4; ++tf)
#pragma unroll
                    for (int r = 0; r < 4; ++r) {
                        float pv = __expf(s[tf][r] - mrow[sub]);
                        s[tf][r] = pv;
                        rs += pv;
                    }
                rs += __shfl_xor(rs, 16);
                rs += __shfl_xor(rs, 32);
                lrow[sub] += rs;

                // pack P -> wave-private LDS (per-sub buffer reuse)
#pragma unroll
                for (int tf = 0; tf < 4; ++tf)
#pragma unroll
                    for (int rp = 0; rp < 2; ++rp) {
                        unsigned int w = ((unsigned int)bfbits(s[tf][2 * rp + 1]) << 16) |
                                         bfbits(s[tf][2 * rp]);
                        Pk[wid][m][(8 * tf + 2 * h + rp) ^ swz] = w;
                    }

                // ---- PV ----
                __builtin_amdgcn_s_setprio(1);
#pragma unroll
                for (int kc = 0; kc < 2; ++kc) {
                    bf16x8 ap = *(bf16x8*)&Pk[wid][m][(16 * kc + 4 * h) ^ swz];
#pragma unroll
                    for (int nf = 0; nf < 4; ++nf)
                        o[sub][nf] = __builtin_amdgcn_mfma_f32_16x16x32_bf16(
                            ap, vf[nf][kc], o[sub][nf], 0, 0, 0);
                }
                __builtin_amdgcn_s_setprio(0);
            }
        }
        __builtin_amdgcn_s_barrier();  // all reads of buf[cur] done; safe to overwrite
        cur ^= 1;
    }
#undef STAGE

    // ---- direct write-out (no merge: waves own distinct q-rows) ----
    const int b_ = bh >> 4, hh = bh & 15;
#pragma unroll
    for (int sub = 0; sub < 2; ++sub) {
        float lc = lrow[sub];
        float lcr[4];
#pragma unroll
        for (int r = 0; r < 4; ++r) lcr[r] = __shfl(lc, 20 * h + r);
#pragma unroll
        for (int nf = 0; nf < 4; ++nf)
#pragma unroll
            for (int r = 0; r < 4; ++r) {
                float val = o[sub][nf][r] / lcr[r];
                int s_ = q0 + sub * 16 + h * 4 + r;
                AO[((size_t)(b_ * SEQ + s_)) * D_MODEL + hh * HEAD_DIM + nf * 16 + m] =
                    (bf16)val;
            }
    }
}

extern "C" void kernel_launch(void* const* d_in, const int* in_sizes, int n_in,
                              void* d_out, int out_size, void* d_ws, size_t ws_size,
                              hipStream_t stream) {
    const float* x  = (const float*)d_in[0];
    const float* Wq = (const float*)d_in[1];
    const float* bq = (const float*)d_in[2];
    const float* Wk = (const float*)d_in[3];
    const float* bk = (const float*)d_in[4];
    const float* Wv = (const float*)d_in[5];
    const float* bv = (const float*)d_in[6];
    const float* Wo = (const float*)d_in[7];
    const float* bo = (const float*)d_in[8];

    char* ws = (char*)d_ws;
    const size_t MB = 1u << 20;
    bf16* wt = (bf16*)ws;                  // 4 x [1024][1024] bf16 (QKV contiguous)
    bf16* xb = (bf16*)(ws + 8 * MB);       // [4096][1024] bf16
    bf16* Qb = (bf16*)(ws + 16 * MB);      // Q*0.125 [32][2048][64]; K; V^T [32][64][2048]
    bf16* AO = (bf16*)(ws + 40 * MB);      // [4096][1024] bf16

    const size_t WSTRIDE = (size_t)D_MODEL * D_MODEL;

    cvt_x<<<dim3(MROWS * D_MODEL / 4 / 256), dim3(256), 0, stream>>>(x, xb);
    cvt_wt<<<dim3(32, 32, 4), dim3(32, 32), 0, stream>>>(Wq, Wk, Wv, Wo, wt);

    gemm_k<0><<<dim3(24, 32), dim3(256), 0, stream>>>(xb, wt, bq, bk, bv, Qb);

    bf16* Kb = Qb + 4194304;
    bf16* VTb = Qb + 2 * 4194304;
    attn_k<<<dim3(512), dim3(256), 0, stream>>>(Qb, Kb, VTb, AO);

    gemm_k<1><<<dim3(8, 32), dim3(256), 0, stream>>>(AO, wt + 3 * WSTRIDE, bo, bo, bo, d_out);
}

// Round 18
// 126.307 us; speedup vs baseline: 1.4336x; 1.1287x over previous
//
#include <hip/hip_runtime.h>
#include <hip/hip_bf16.h>
#include <cmath>

#define D_MODEL 1024
#define N_HEADS 16
#define HEAD_DIM 64
#define SEQ 2048
#define BATCH 2
#define MROWS (BATCH * SEQ)  // 4096

typedef __bf16 bf16;
typedef __bf16 bf16x8 __attribute__((ext_vector_type(8)));
typedef __bf16 bf16x4 __attribute__((ext_vector_type(4)));
typedef float f32x4 __attribute__((ext_vector_type(4)));

// GEMM LDS swizzle (64B rows): byte = row*64 + (cbyte ^ (((row>>1)&3)<<4))
#define SWZG(row, cbyte) ((row) * 64 + ((cbyte) ^ ((((row) >> 1) & 3) << 4)))

// async global->LDS, 16B per lane, linear dest (wave base + lane*16)
#define GLOAD16(g, l)                                                        \
    __builtin_amdgcn_global_load_lds(                                        \
        (const __attribute__((address_space(1))) void*)(g),                  \
        (__attribute__((address_space(3))) void*)(l), 16, 0, 0)

static __device__ __forceinline__ unsigned short bfbits(float f) {
    bf16 b = (bf16)f;
    return *(unsigned short*)&b;
}

// ---------------- fp32 -> bf16 convert (x) ----------------
__global__ __launch_bounds__(256) void cvt_x(const float* __restrict__ x,
                                             bf16* __restrict__ xb) {
    int i = blockIdx.x * 256 + threadIdx.x;
    float4 v = ((const float4*)x)[i];
    bf16x4 o = { (bf16)v.x, (bf16)v.y, (bf16)v.z, (bf16)v.w };
    ((bf16x4*)xb)[i] = o;
}

// ---------------- weight transpose + convert: wt[z][n][k] = W_z[k][n] ----------------
__global__ void cvt_wt(const float* __restrict__ Wq, const float* __restrict__ Wk,
                       const float* __restrict__ Wv, const float* __restrict__ Wo,
                       bf16* __restrict__ wt) {
    __shared__ float tile[32][33];
    int z = blockIdx.z;
    const float* W = (z == 0) ? Wq : (z == 1) ? Wk : (z == 2) ? Wv : Wo;
    int n0 = blockIdx.x * 32, k0 = blockIdx.y * 32;
    int tx = threadIdx.x, ty = threadIdx.y;
    tile[ty][tx] = W[(size_t)(k0 + ty) * D_MODEL + n0 + tx];
    __syncthreads();
    wt[(size_t)z * D_MODEL * D_MODEL + (size_t)(n0 + ty) * D_MODEL + k0 + tx] =
        (bf16)tile[tx][ty];
}

// ---------------- GEMM: Y[M,N] = A[M,K] @ Wt[N,K]^T + bias (BK=32, proven) ----------------
template <int MODE>
__global__ __launch_bounds__(256) void gemm_k(const bf16* __restrict__ A,
                                              const bf16* __restrict__ Bt,
                                              const float* __restrict__ b0,
                                              const float* __restrict__ b1,
                                              const float* __restrict__ b2,
                                              void* __restrict__ outp) {
    constexpr int BM = 128, BK = 32, KDIM = D_MODEL;
    __shared__ alignas(16) bf16 As[BM * BK];
    __shared__ alignas(16) bf16 Bs[BM * BK];
    char* Asb = (char*)As;
    char* Bsb = (char*)Bs;
    const int tid = threadIdx.x;
    const int wid = tid >> 6, lane = tid & 63;
    const int m0 = blockIdx.y * BM, n0 = blockIdx.x * BM;
    const int wr = (wid >> 1) * 64, wc = (wid & 1) * 64;
    f32x4 acc[4][4] = {};

    for (int k0 = 0; k0 < KDIM; k0 += BK) {
        __syncthreads();
#pragma unroll
        for (int c = 0; c < 2; ++c) {
            const int q = c * 4 + wid;
            const int row = q * 16 + (lane >> 2);
            const int col = (lane & 3) ^ ((row >> 1) & 3);
            GLOAD16(&A[(size_t)(m0 + row) * KDIM + k0 + col * 8], Asb + q * 1024);
            GLOAD16(&Bt[(size_t)(n0 + row) * KDIM + k0 + col * 8], Bsb + q * 1024);
        }
        __syncthreads();
        const int cb = (lane >> 4) * 16;
        bf16x8 a[4], b[4];
#pragma unroll
        for (int m = 0; m < 4; ++m) {
            int r = wr + m * 16 + (lane & 15);
            a[m] = *(bf16x8*)(Asb + SWZG(r, cb));
        }
#pragma unroll
        for (int n = 0; n < 4; ++n) {
            int r = wc + n * 16 + (lane & 15);
            b[n] = *(bf16x8*)(Bsb + SWZG(r, cb));
        }
#pragma unroll
        for (int m = 0; m < 4; ++m)
#pragma unroll
            for (int n = 0; n < 4; ++n)
                acc[m][n] = __builtin_amdgcn_mfma_f32_16x16x32_bf16(a[m], b[n], acc[m][n], 0, 0, 0);
    }

    const int z = n0 >> 10;
    const float* bias = (MODE == 1) ? b0 : ((z == 0) ? b0 : (z == 1) ? b1 : b2);
#pragma unroll
    for (int m = 0; m < 4; ++m)
#pragma unroll
        for (int n = 0; n < 4; ++n)
#pragma unroll
            for (int r = 0; r < 4; ++r) {
                int grow = m0 + wr + m * 16 + (lane >> 4) * 4 + r;
                int gcol = n0 + wc + n * 16 + (lane & 15);
                if (MODE == 0) {
                    int colN = gcol & 1023;
                    float val = acc[m][n][r] + bias[colN];
                    if (z == 0) val *= 0.125f;  // fold attn scale into Q
                    int b_ = grow >> 11, s_ = grow & 2047;
                    int h = colN >> 6, hd = colN & 63;
                    if (z == 2) {
                        ((bf16*)outp)[(size_t)z * 4194304 +
                                      ((size_t)(b_ * N_HEADS + h) * HEAD_DIM + hd) * SEQ + s_] =
                            (bf16)val;
                    } else {
                        ((bf16*)outp)[(size_t)z * 4194304 +
                                      ((size_t)(b_ * N_HEADS + h) * SEQ + s_) * HEAD_DIM + hd] =
                            (bf16)val;
                    }
                } else {
                    float val = acc[m][n][r] + bias[gcol];
                    ((float*)outp)[(size_t)grow * D_MODEL + gcol] = val;
                }
            }
}

// ---------------- flash attention: block-shared LDS K/V, 8 waves x 16 q-rows ----------------
// grid 512 x 512 threads. Block = 128-row band (8 waves x 16 rows); heavy first.
// 16 rows/wave doubles wave count (4096 = 4/SIMD) at CONSTANT traffic: K/V staged
// per-block (not per-wave) via global_load_lds into double-buffered XOR-swizzled
// LDS. Counted vmcnt(2) + 2 raw s_barrier per tile; no vmcnt(0) drain in loop.
// Swapped QK^T, per-lane softmax stats, packed-P PV; no merge (waves own rows).
__global__ __launch_bounds__(512) void attn_k(const bf16* __restrict__ Qg,
                                              const bf16* __restrict__ Kg,
                                              const bf16* __restrict__ VTg,
                                              bf16* __restrict__ AO) {
    __shared__ alignas(16) bf16 Ks[2][64 * 64];         // 16 KB
    __shared__ alignas(16) bf16 Vs[2][64 * 64];         // 16 KB
    __shared__ alignas(16) unsigned int Pk[8][16][32];  // 16 KB
    const int tid = threadIdx.x, wid = tid >> 6, lane = tid & 63;
    const int m = lane & 15, h = lane >> 4;
    const int band = 15 - (int)(blockIdx.x >> 5);  // heavy first
    const int bh = blockIdx.x & 31;                // bh%8 fixes XCD -> KV L2 locality
    const int q0 = band * 128 + wid * 16;
    const size_t base = (size_t)bh * SEQ * HEAD_DIM;
    const bf16* VT = VTg + (size_t)bh * HEAD_DIM * SEQ;
    const int swz = (m & 7) << 2;
    const int nt_w = band * 2 + (wid >> 2) + 1;  // this wave's tiles
    const int nt_blk = band * 2 + 2;             // block's staged tiles

    bf16x8 aq[2];
#pragma unroll
    for (int kc = 0; kc < 2; ++kc)
        aq[kc] = *(const bf16x8*)
            &Qg[base + (size_t)(q0 + m) * HEAD_DIM + kc * 32 + h * 8];

    f32x4 o[4] = {};
    float mrow = -__builtin_inff();
    float lrow = 0.f;

    // stage tile T0 into buffer BUF: 1 K + 1 V GLOAD16 per thread (512 threads).
    // LDS slot s of row holds global col 8*(s^(row&7)) (inverse swizzle at source).
#define STAGE(T0, BUF)                                                            \
    {                                                                             \
        int row = tid >> 3, sl = tid & 7;                                         \
        GLOAD16(&Kg[base + (size_t)((T0) + row) * HEAD_DIM + 8 * (sl ^ (row & 7))], \
                (char*)&Ks[BUF][0] + tid * 16);                                   \
        GLOAD16(&VT[(size_t)row * SEQ + (T0) + 8 * (sl ^ (row & 7))],             \
                (char*)&Vs[BUF][0] + tid * 16);                                   \
    }

    STAGE(0, 0);
    int cur = 0;
    for (int it = 0; it < nt_blk; ++it) {
        if (it + 1 < nt_blk) {
            STAGE((it + 1) * 64, cur ^ 1);
            asm volatile("s_waitcnt vmcnt(2)" ::: "memory");  // current tile landed
        } else {
            asm volatile("s_waitcnt vmcnt(0)" ::: "memory");
        }
        __builtin_amdgcn_s_barrier();  // all waves' stage of tile it complete

        if (it < nt_w) {
            const int t0 = it * 64;
            char* Kb = (char*)&Ks[cur][0];
            char* Vb = (char*)&Vs[cur][0];
            bf16x8 kf[4][2], vf[4][2];
#pragma unroll
            for (int tf = 0; tf < 4; ++tf)
#pragma unroll
                for (int kc = 0; kc < 2; ++kc)
                    kf[tf][kc] = *(bf16x8*)(Kb + (16 * tf + m) * 128 +
                                            (((4 * kc + h) ^ (m & 7)) << 4));
#pragma unroll
            for (int nf = 0; nf < 4; ++nf)
#pragma unroll
                for (int kc = 0; kc < 2; ++kc)
                    vf[nf][kc] = *(bf16x8*)(Vb + (16 * nf + m) * 128 +
                                            (((4 * kc + h) ^ (m & 7)) << 4));

            // ---- QK^T swapped: lane holds q=m, t=16tf+4h+r ----
            f32x4 s[4];
            __builtin_amdgcn_s_setprio(1);
#pragma unroll
            for (int tf = 0; tf < 4; ++tf) {
                f32x4 z = {};
                z = __builtin_amdgcn_mfma_f32_16x16x32_bf16(kf[tf][0], aq[0], z, 0, 0, 0);
                z = __builtin_amdgcn_mfma_f32_16x16x32_bf16(kf[tf][1], aq[1], z, 0, 0, 0);
                s[tf] = z;
            }
            __builtin_amdgcn_s_setprio(0);

            if (it == nt_w - 1) {
#pragma unroll
                for (int tf = 0; tf < 4; ++tf)
#pragma unroll
                    for (int r = 0; r < 4; ++r) {
                        int gq = q0 + m;
                        int gt = t0 + tf * 16 + h * 4 + r;
                        if (gt > gq) s[tf][r] = -__builtin_inff();
                    }
            }

            // ---- online softmax (per-lane stats, defer-max) ----
            float mx = s[0][0];
#pragma unroll
            for (int tf = 0; tf < 4; ++tf)
#pragma unroll
                for (int r = 0; r < 4; ++r) mx = fmaxf(mx, s[tf][r]);
            mx = fmaxf(mx, __shfl_xor(mx, 16));
            mx = fmaxf(mx, __shfl_xor(mx, 32));
            if (!__all(mx <= mrow + 8.f)) {
                float mn = fmaxf(mrow, mx);
                float sf = __expf(mrow - mn);
                mrow = mn;
                lrow *= sf;
                float sfr[4];
#pragma unroll
                for (int r = 0; r < 4; ++r) sfr[r] = __shfl(sf, 20 * h + r);
#pragma unroll
                for (int nf = 0; nf < 4; ++nf)
#pragma unroll
                    for (int r = 0; r < 4; ++r) o[nf][r] *= sfr[r];
            }
            float rs = 0.f;
#pragma unroll
            for (int tf = 0; tf < 4; ++tf)
#pragma unroll
                for (int r = 0; r < 4; ++r) {
                    float pv = __expf(s[tf][r] - mrow);
                    s[tf][r] = pv;
                    rs += pv;
                }
            rs += __shfl_xor(rs, 16);
            rs += __shfl_xor(rs, 32);
            lrow += rs;

            // pack P -> wave-private LDS
#pragma unroll
            for (int tf = 0; tf < 4; ++tf)
#pragma unroll
                for (int rp = 0; rp < 2; ++rp) {
                    unsigned int w = ((unsigned int)bfbits(s[tf][2 * rp + 1]) << 16) |
                                     bfbits(s[tf][2 * rp]);
                    Pk[wid][m][(8 * tf + 2 * h + rp) ^ swz] = w;
                }

            // ---- PV ----
            __builtin_amdgcn_s_setprio(1);
#pragma unroll
            for (int kc = 0; kc < 2; ++kc) {
                bf16x8 ap = *(bf16x8*)&Pk[wid][m][(16 * kc + 4 * h) ^ swz];
#pragma unroll
                for (int nf = 0; nf < 4; ++nf)
                    o[nf] = __builtin_amdgcn_mfma_f32_16x16x32_bf16(
                        ap, vf[nf][kc], o[nf], 0, 0, 0);
            }
            __builtin_amdgcn_s_setprio(0);
        }
        __builtin_amdgcn_s_barrier();  // all reads of buf[cur] done; safe to overwrite
        cur ^= 1;
    }
#undef STAGE

    // ---- direct write-out (no merge: waves own distinct q-rows) ----
    const int b_ = bh >> 4, hh = bh & 15;
    float lcr[4];
#pragma unroll
    for (int r = 0; r < 4; ++r) lcr[r] = __shfl(lrow, 20 * h + r);
#pragma unroll
    for (int nf = 0; nf < 4; ++nf)
#pragma unroll
        for (int r = 0; r < 4; ++r) {
            float val = o[nf][r] / lcr[r];
            int s_ = q0 + h * 4 + r;
            AO[((size_t)(b_ * SEQ + s_)) * D_MODEL + hh * HEAD_DIM + nf * 16 + m] =
                (bf16)val;
        }
}

extern "C" void kernel_launch(void* const* d_in, const int* in_sizes, int n_in,
                              void* d_out, int out_size, void* d_ws, size_t ws_size,
                              hipStream_t stream) {
    const float* x  = (const float*)d_in[0];
    const float* Wq = (const float*)d_in[1];
    const float* bq = (const float*)d_in[2];
    const float* Wk = (const float*)d_in[3];
    const float* bk = (const float*)d_in[4];
    const float* Wv = (const float*)d_in[5];
    const float* bv = (const float*)d_in[6];
    const float* Wo = (const float*)d_in[7];
    const float* bo = (const float*)d_in[8];

    char* ws = (char*)d_ws;
    const size_t MB = 1u << 20;
    bf16* wt = (bf16*)ws;                  // 4 x [1024][1024] bf16 (QKV contiguous)
    bf16* xb = (bf16*)(ws + 8 * MB);       // [4096][1024] bf16
    bf16* Qb = (bf16*)(ws + 16 * MB);      // Q*0.125 [32][2048][64]; K; V^T [32][64][2048]
    bf16* AO = (bf16*)(ws + 40 * MB);      // [4096][1024] bf16

    const size_t WSTRIDE = (size_t)D_MODEL * D_MODEL;

    cvt_x<<<dim3(MROWS * D_MODEL / 4 / 256), dim3(256), 0, stream>>>(x, xb);
    cvt_wt<<<dim3(32, 32, 4), dim3(32, 32), 0, stream>>>(Wq, Wk, Wv, Wo, wt);

    gemm_k<0><<<dim3(24, 32), dim3(256), 0, stream>>>(xb, wt, bq, bk, bv, Qb);

    bf16* Kb = Qb + 4194304;
    bf16* VTb = Qb + 2 * 4194304;
    attn_k<<<dim3(512), dim3(512), 0, stream>>>(Qb, Kb, VTb, AO);

    gemm_k<1><<<dim3(8, 32), dim3(256), 0, stream>>>(AO, wt + 3 * WSTRIDE, bo, bo, bo, d_out);
}